// Round 6
// baseline (798.772 us; speedup 1.0000x reference)
//
#include <hip/hip_runtime.h>
#include <hip/hip_bf16.h>
#include <math.h>

#define SCAN_CHUNK 2048

typedef _Float16 half2v __attribute__((ext_vector_type(2)));
typedef _Float16 half8 __attribute__((ext_vector_type(8)));
typedef float floatx4 __attribute__((ext_vector_type(4)));

#if defined(__has_builtin)
#if __has_builtin(__builtin_amdgcn_fdot2)
#define USE_FDOT2 1
#endif
#endif

// ---------------- CSR build ----------------

__global__ void hist_kernel(const int* __restrict__ dst, int* __restrict__ counts, int e) {
    int i = blockIdx.x * blockDim.x + threadIdx.x;
    if (i < e) atomicAdd(&counts[dst[i]], 1);
}

__global__ __launch_bounds__(256) void scan_block_sums(const int* __restrict__ counts,
                                                       int* __restrict__ bsum, int n) {
    __shared__ int sd[256];
    int t = threadIdx.x;
    int base = blockIdx.x * SCAN_CHUNK + t * 8;
    int s = 0;
#pragma unroll
    for (int j = 0; j < 8; ++j) {
        int idx = base + j;
        if (idx < n) s += counts[idx];
    }
    sd[t] = s;
    __syncthreads();
    for (int off = 128; off > 0; off >>= 1) {
        if (t < off) sd[t] += sd[t + off];
        __syncthreads();
    }
    if (t == 0) bsum[blockIdx.x] = sd[0];
}

// single-wave exclusive scan over nb <= 64 block sums
__global__ void scan_wave(int* bsum, int nb) {
    int lane = threadIdx.x;
    int orig = (lane < nb) ? bsum[lane] : 0;
    int v = orig;
    for (int off = 1; off < 64; off <<= 1) {
        int t = __shfl_up(v, off, 64);
        if (lane >= off) v += t;
    }
    if (lane < nb) bsum[lane] = v - orig;  // exclusive
}

__global__ __launch_bounds__(256) void scan_write(const int* __restrict__ counts,
                                                  const int* __restrict__ bsum,
                                                  int* __restrict__ row_ptr,
                                                  int* __restrict__ cursor,
                                                  int n, int total) {
    __shared__ int sd[256];
    int t = threadIdx.x;
    int base = blockIdx.x * SCAN_CHUNK + t * 8;
    int v[8];
    int s = 0;
#pragma unroll
    for (int j = 0; j < 8; ++j) {
        int idx = base + j;
        v[j] = (idx < n) ? counts[idx] : 0;
        s += v[j];
    }
    sd[t] = s;
    __syncthreads();
    for (int off = 1; off < 256; off <<= 1) {
        int tmp = 0;
        if (t >= off) tmp = sd[t - off];
        __syncthreads();
        if (t >= off) sd[t] += tmp;
        __syncthreads();
    }
    int run = bsum[blockIdx.x] + sd[t] - s;
#pragma unroll
    for (int j = 0; j < 8; ++j) {
        int idx = base + j;
        if (idx < n) {
            row_ptr[idx] = run;
            cursor[idx] = run;
            run += v[j];
        }
    }
    if (blockIdx.x == 0 && t == 0) row_ptr[n] = total;
}

// scatter edges into CSR slots as packed 16B records {src, w2, (w0|w1)}.
// pos[i] = slot of edge i (coalesced write); attn_norm gathers slot-ordered pbuf.
__global__ void fill_csr(const int* __restrict__ dst, const int* __restrict__ src,
                         const float* __restrict__ vw, int* cursor,
                         int4* __restrict__ recs, int* __restrict__ pos, int e) {
    int i = blockIdx.x * blockDim.x + threadIdx.x;
    if (i < e) {
        int p = atomicAdd(&cursor[dst[i]], 1);
        float w0 = vw[3 * i], w1 = vw[3 * i + 1], w2 = vw[3 * i + 2];
        unsigned u0 = (unsigned)__builtin_bit_cast(unsigned short, (_Float16)w0);
        unsigned u1 = (unsigned)__builtin_bit_cast(unsigned short, (_Float16)w1);
        unsigned u2 = (unsigned)__builtin_bit_cast(unsigned short, (_Float16)w2);
        int4 r;
        r.x = src[i];
        r.y = (int)u2;
        r.z = (int)(u0 | (u1 << 16));
        r.w = 0;
        recs[p] = r;
        pos[i] = p;
    }
}

// transpose+convert W [k][n] fp32 -> wt [n][k] fp16; blockIdx.x selects matrix
__global__ __launch_bounds__(256) void prep_w(const float* __restrict__ Wq,
                                              const float* __restrict__ Wk,
                                              const float* __restrict__ Wv,
                                              _Float16* __restrict__ wt) {
    const float* W = (blockIdx.x == 0) ? Wq : (blockIdx.x == 1) ? Wk : Wv;
    _Float16* out = wt + (size_t)blockIdx.x * 16384;
    int t = threadIdx.x;
    for (int r = 0; r < 64; ++r) {
        int idx = r * 256 + t;          // idx = k*128 + n
        int k = idx >> 7, nn = idx & 127;
        out[nn * 128 + k] = (_Float16)W[idx];
    }
}

// ---------------- fused QKV projection: fp32 x staged once, 3 GEMMs ----------------
// Outputs: qh [node][128] and kvb [node][h][ k(16) | v(16) ] interleaved so a
// lane's k-half8 and v-half8 share one 64B line in edge_attn's gather.

#define LDP 136  // 128 + 8 halfs pad

__global__ __launch_bounds__(256) void qkv_mfma(
    const float* __restrict__ x, const _Float16* __restrict__ wt,
    const float* __restrict__ bq, const float* __restrict__ bk,
    const float* __restrict__ bv,
    _Float16* __restrict__ qh, _Float16* __restrict__ kvb, int n) {
    __shared__ __align__(16) _Float16 xs[128 * LDP];
    __shared__ __align__(16) _Float16 ws[128 * LDP];

    int t = threadIdx.x;
    int tile0 = blockIdx.x * 128;

    // stage x tile fp32 -> fp16 (128 rows x 16 half8 chunks)
#pragma unroll
    for (int r = 0; r < 8; ++r) {
        int id = r * 256 + t;
        int row = id >> 4, c8 = id & 15;
        int grow = tile0 + row;
        half8 val = (half8)(_Float16)0;
        if (grow < n) {
            const float4* s = (const float4*)(x + (size_t)grow * 128 + c8 * 8);
            float4 a = s[0], b = s[1];
            val[0] = (_Float16)a.x; val[1] = (_Float16)a.y;
            val[2] = (_Float16)a.z; val[3] = (_Float16)a.w;
            val[4] = (_Float16)b.x; val[5] = (_Float16)b.y;
            val[6] = (_Float16)b.z; val[7] = (_Float16)b.w;
        }
        *((half8*)(xs + row * LDP) + c8) = val;
    }

    int wave = t >> 6, lane = t & 63;
    int wm = (wave & 1) * 64, wn = (wave >> 1) * 64;
    int lrow = lane & 15, quad = lane >> 4;

    for (int sel = 0; sel < 3; ++sel) {
        const _Float16* wsel = wt + (size_t)sel * 16384;
        const float* bias = (sel == 0) ? bq : (sel == 1) ? bk : bv;

        // stage W^T tile
#pragma unroll
        for (int r = 0; r < 8; ++r) {
            int id = r * 256 + t;
            int row = id >> 4, c8 = id & 15;
            half8 wv = *((const half8*)(wsel + row * 128) + c8);
            *((half8*)(ws + row * LDP) + c8) = wv;
        }
        __syncthreads();

        floatx4 acc[4][4];
#pragma unroll
        for (int i = 0; i < 4; ++i)
#pragma unroll
            for (int j = 0; j < 4; ++j) acc[i][j] = (floatx4)0.f;

#pragma unroll
        for (int kk = 0; kk < 4; ++kk) {
            int kbase = kk * 32 + quad * 8;
            half8 a[4], b[4];
#pragma unroll
            for (int i = 0; i < 4; ++i)
                a[i] = *(const half8*)(xs + (wm + i * 16 + lrow) * LDP + kbase);
#pragma unroll
            for (int j = 0; j < 4; ++j)
                b[j] = *(const half8*)(ws + (wn + j * 16 + lrow) * LDP + kbase);
#pragma unroll
            for (int i = 0; i < 4; ++i)
#pragma unroll
                for (int j = 0; j < 4; ++j)
                    acc[i][j] = __builtin_amdgcn_mfma_f32_16x16x32_f16(a[i], b[j], acc[i][j], 0, 0, 0);
        }

        // epilogue: C row = wm+i*16+quad*4+reg, col = wn+j*16+lrow
#pragma unroll
        for (int i = 0; i < 4; ++i) {
#pragma unroll
            for (int j = 0; j < 4; ++j) {
                int col = wn + j * 16 + lrow;
                float bv_ = bias[col];
                int h = col >> 4, dh = col & 15;
#pragma unroll
                for (int r = 0; r < 4; ++r) {
                    int row = wm + i * 16 + quad * 4 + r;
                    int grow = tile0 + row;
                    if (grow < n) {
                        _Float16 val = (_Float16)(acc[i][j][r] + bv_);
                        if (sel == 0)
                            qh[(size_t)grow * 128 + col] = val;
                        else
                            kvb[(size_t)grow * 256 + h * 32 + dh +
                                (sel == 2 ? 16 : 0)] = val;
                    }
                }
            }
        }
        __syncthreads();  // all waves done with ws before next sel restages
    }
}

// ---------------- Node-centric attention: 16 thr/node, depth-2 pipeline ----------------
// 2 lanes per head (8 elems each). K/V interleaved per (node,head): a lane's
// k and v half8 live in the SAME 64B line -> one L1-missing access per edge
// per lane instead of two. mix from packed slot record (broadcast int4).
// pbuf slot-indexed (contiguous per node). 4 named KV slots, two alternating
// bodies. 128-thread blocks (8 nodes, 2 waves/wg) to clear the per-CU
// workgroup-count occupancy cap seen with 64-thread blocks.

#define STAGE_META(S, idx)                                                    \
    {                                                                         \
        s##S = 0; m##S = 0.f;                                                 \
        if ((idx) < end) {                                                    \
            int4 r_ = recs[(idx)];                                            \
            s##S = r_.x;                                                      \
            half2v w01_ = __builtin_bit_cast(half2v, r_.z);                   \
            _Float16 w2_ =                                                    \
                __builtin_bit_cast(_Float16, (unsigned short)(unsigned)r_.y); \
            m##S = fmaf(p0, (float)w01_[0],                                   \
                        fmaf(p1, (float)w01_[1], p2 * (float)w2_));           \
        }                                                                     \
    }

#define ISSUE_KV(S, idx)                                                      \
    {                                                                         \
        k##S = (half8)(_Float16)0; v##S = (half8)(_Float16)0;                 \
        if ((idx) < end) {                                                    \
            const _Float16* kp_ = kvbase + (size_t)s##S * 256;                \
            k##S = *(const half8*)(kp_);                                      \
            v##S = *(const half8*)(kp_ + 16);                                 \
        }                                                                     \
    }

#ifdef USE_FDOT2
#define DOT8(dres, kS)                                                        \
    {                                                                         \
        _Pragma("unroll")                                                     \
        for (int jj_ = 0; jj_ < 4; ++jj_) {                                   \
            half2v x_, y_;                                                    \
            x_[0] = qv[2 * jj_]; x_[1] = qv[2 * jj_ + 1];                     \
            y_[0] = kS[2 * jj_]; y_[1] = kS[2 * jj_ + 1];                     \
            dres = __builtin_amdgcn_fdot2(x_, y_, dres, false);               \
        }                                                                     \
    }
#else
#define DOT8(dres, kS)                                                        \
    {                                                                         \
        _Pragma("unroll")                                                     \
        for (int jj_ = 0; jj_ < 8; ++jj_)                                     \
            dres = fmaf((float)qv[jj_], (float)kS[jj_], dres);                \
    }
#endif

#define COMPUTE(S, mx, slot, validc)                                          \
    {                                                                         \
        float d_ = 0.f;                                                       \
        DOT8(d_, k##S);                                                       \
        d_ += __shfl_xor(d_, 1, 64);                                          \
        float p_ = ((mx) > 0.f) ? (mx)*__expf(d_ * 0.25f) : 0.f;              \
        if (sub == 0 && (validc)) pbuf[(size_t)(slot)*8 + h] = (_Float16)p_;  \
        l += p_;                                                              \
        a0 = fmaf(p_, (float)v##S[0], a0);                                    \
        a1 = fmaf(p_, (float)v##S[1], a1);                                    \
        a2 = fmaf(p_, (float)v##S[2], a2);                                    \
        a3 = fmaf(p_, (float)v##S[3], a3);                                    \
        a4 = fmaf(p_, (float)v##S[4], a4);                                    \
        a5 = fmaf(p_, (float)v##S[5], a5);                                    \
        a6 = fmaf(p_, (float)v##S[6], a6);                                    \
        a7 = fmaf(p_, (float)v##S[7], a7);                                    \
    }

#define BODY(S0, S1, S2, S3, jj)                                              \
    {                                                                         \
        ISSUE_KV(S2, (jj) + 2);                                               \
        ISSUE_KV(S3, (jj) + 3);                                               \
        float mx0_ = m##S0, mx1_ = m##S1;                                     \
        STAGE_META(S0, (jj) + 4);                                             \
        STAGE_META(S1, (jj) + 5);                                             \
        COMPUTE(S0, mx0_, (jj), true);                                        \
        COMPUTE(S1, mx1_, (jj) + 1, (jj) + 1 < end);                          \
    }

__global__ __launch_bounds__(128, 8) void edge_attn(
    const _Float16* __restrict__ qh, const _Float16* __restrict__ kvb,
    const float* __restrict__ pi,
    const int* __restrict__ row_ptr, const int4* __restrict__ recs,
    float* __restrict__ node_out, float* __restrict__ invb,
    _Float16* __restrict__ pbuf, int n) {
    int t = threadIdx.x;
    int node = blockIdx.x * 8 + (t >> 4);
    if (node >= n) return;
    int q16 = t & 15;
    int h = q16 >> 1, sub = q16 & 1;
    int off = h * 16 + sub * 8;  // element offset within 128-wide q row

    const half8 qv = *(const half8*)(qh + (size_t)node * 128 + off);
    const _Float16* kvbase = kvb + h * 32 + sub * 8;  // + s*256 -> k; +16 -> v

    float p0 = pi[node * 24 + h * 3 + 0];
    float p1 = pi[node * 24 + h * 3 + 1];
    float p2 = pi[node * 24 + h * 3 + 2];
    int beg = row_ptr[node], end = row_ptr[node + 1];

    float l = 0.f;
    float a0 = 0.f, a1 = 0.f, a2 = 0.f, a3 = 0.f;
    float a4 = 0.f, a5 = 0.f, a6 = 0.f, a7 = 0.f;

    int sA, sB, sC, sD;
    float mA, mB, mC, mD;
    half8 kA, vA, kB, vB, kC, vC, kD, vD;

    STAGE_META(A, beg);
    STAGE_META(B, beg + 1);
    STAGE_META(C, beg + 2);
    STAGE_META(D, beg + 3);
    ISSUE_KV(A, beg);
    ISSUE_KV(B, beg + 1);

    for (int j = beg; j < end;) {
        BODY(A, B, C, D, j);
        j += 2;
        if (j >= end) break;
        BODY(C, D, A, B, j);
        j += 2;
    }

    float inv = 1.f / fmaxf(l, 1e-8f);
    if (sub == 0) invb[(size_t)node * 8 + h] = inv;

    float4* op = (float4*)(node_out + (size_t)node * 128 + off);
    op[0] = make_float4(a0 * inv, a1 * inv, a2 * inv, a3 * inv);
    op[1] = make_float4(a4 * inv, a5 * inv, a6 * inv, a7 * inv);
}

// ---------------- edge-parallel attention normalize ----------------
// pbuf slot-ordered; pos[i] maps edge -> slot (coalesced 4B read). pbuf gather
// is 16B from an L2/L3-resident 25.6MB buffer. Output write coalesced.

__global__ __launch_bounds__(256) void attn_norm(
    const _Float16* __restrict__ pbuf, const int* __restrict__ dst,
    const int* __restrict__ pos, const float* __restrict__ invb,
    float* __restrict__ attn_out, int e) {
    int i = blockIdx.x * blockDim.x + threadIdx.x;
    if (i < e) {
        int d = dst[i];
        int p = pos[i];
        half8 pv = *((const half8*)pbuf + p);
        const float4* iv = (const float4*)(invb + (size_t)d * 8);
        float4 i0 = iv[0], i1 = iv[1];
        float4* op = (float4*)(attn_out + (size_t)i * 8);
        op[0] = make_float4((float)pv[0] * i0.x, (float)pv[1] * i0.y,
                            (float)pv[2] * i0.z, (float)pv[3] * i0.w);
        op[1] = make_float4((float)pv[4] * i1.x, (float)pv[5] * i1.y,
                            (float)pv[6] * i1.z, (float)pv[7] * i1.w);
    }
}

// ---------------- launch ----------------

extern "C" void kernel_launch(void* const* d_in, const int* in_sizes, int n_in,
                              void* d_out, int out_size, void* d_ws, size_t ws_size,
                              hipStream_t stream) {
    const float* x  = (const float*)d_in[0];
    const float* pi = (const float*)d_in[1];
    const float* vw = (const float*)d_in[2];
    const float* Wq = (const float*)d_in[3];
    const float* bq = (const float*)d_in[4];
    const float* Wk = (const float*)d_in[5];
    const float* bk = (const float*)d_in[6];
    const float* Wv = (const float*)d_in[7];
    const float* bv = (const float*)d_in[8];
    const int* src  = (const int*)d_in[9];
    const int* dst  = (const int*)d_in[10];

    int n = in_sizes[0] / 128;  // 100000
    int e = in_sizes[9];        // 1600000

    _Float16* qh  = (_Float16*)d_ws;
    _Float16* kvb = qh + (size_t)n * 128;
    _Float16* wt  = kvb + (size_t)n * 256;
    _Float16* pbuf = wt + 3 * 16384;
    float* invb  = (float*)(pbuf + (size_t)e * 8);
    int* counts  = (int*)(invb + (size_t)n * 8);
    int* cursor  = counts + n;
    int* row_ptr = cursor + n;
    int* bsum    = row_ptr + n + 1;
    int* pos     = bsum + 64;

    float* node_out = (float*)d_out;
    float* attn_out = node_out + (size_t)n * 128;
    // recs scratch (16B/edge = 25.6MB) lives in the 51.2MB attn output region:
    // written by fill_csr, consumed by edge_attn, overwritten by attn_norm.
    int4* recs = (int4*)attn_out;

    hipMemsetAsync(counts, 0, (size_t)n * sizeof(int), stream);

    int eb = (e + 255) / 256;
    hist_kernel<<<eb, 256, 0, stream>>>(dst, counts, e);

    int nb = (n + SCAN_CHUNK - 1) / SCAN_CHUNK;  // 49
    scan_block_sums<<<nb, 256, 0, stream>>>(counts, bsum, n);
    scan_wave<<<1, 64, 0, stream>>>(bsum, nb);
    scan_write<<<nb, 256, 0, stream>>>(counts, bsum, row_ptr, cursor, n, e);
    fill_csr<<<eb, 256, 0, stream>>>(dst, src, vw, cursor, recs, pos, e);

    prep_w<<<3, 256, 0, stream>>>(Wq, Wk, Wv, wt);

    int gtiles = (n + 127) / 128;
    qkv_mfma<<<gtiles, 256, 0, stream>>>(x, wt, bq, bk, bv, qh, kvb, n);

    int gb = (n + 7) / 8;
    edge_attn<<<gb, 128, 0, stream>>>(qh, kvb, pi, row_ptr, recs,
                                      node_out, invb, pbuf, n);
    attn_norm<<<eb, 256, 0, stream>>>(pbuf, dst, pos, invb, attn_out, e);
}

// Round 7
// 640.159 us; speedup vs baseline: 1.2478x; 1.2478x over previous
//
#include <hip/hip_runtime.h>
#include <hip/hip_bf16.h>
#include <math.h>

#define SCAN_CHUNK 2048

typedef _Float16 half2v __attribute__((ext_vector_type(2)));
typedef _Float16 half8 __attribute__((ext_vector_type(8)));
typedef float floatx4 __attribute__((ext_vector_type(4)));

#if defined(__has_builtin)
#if __has_builtin(__builtin_amdgcn_fdot2)
#define USE_FDOT2 1
#endif
#endif

// ---------------- CSR build ----------------

__global__ void hist_kernel(const int* __restrict__ dst, int* __restrict__ counts, int e) {
    int i = blockIdx.x * blockDim.x + threadIdx.x;
    if (i < e) atomicAdd(&counts[dst[i]], 1);
}

__global__ __launch_bounds__(256) void scan_block_sums(const int* __restrict__ counts,
                                                       int* __restrict__ bsum, int n) {
    __shared__ int sd[256];
    int t = threadIdx.x;
    int base = blockIdx.x * SCAN_CHUNK + t * 8;
    int s = 0;
#pragma unroll
    for (int j = 0; j < 8; ++j) {
        int idx = base + j;
        if (idx < n) s += counts[idx];
    }
    sd[t] = s;
    __syncthreads();
    for (int off = 128; off > 0; off >>= 1) {
        if (t < off) sd[t] += sd[t + off];
        __syncthreads();
    }
    if (t == 0) bsum[blockIdx.x] = sd[0];
}

// single-wave exclusive scan over nb <= 64 block sums
__global__ void scan_wave(int* bsum, int nb) {
    int lane = threadIdx.x;
    int orig = (lane < nb) ? bsum[lane] : 0;
    int v = orig;
    for (int off = 1; off < 64; off <<= 1) {
        int t = __shfl_up(v, off, 64);
        if (lane >= off) v += t;
    }
    if (lane < nb) bsum[lane] = v - orig;  // exclusive
}

__global__ __launch_bounds__(256) void scan_write(const int* __restrict__ counts,
                                                  const int* __restrict__ bsum,
                                                  int* __restrict__ row_ptr,
                                                  int* __restrict__ cursor,
                                                  int n, int total) {
    __shared__ int sd[256];
    int t = threadIdx.x;
    int base = blockIdx.x * SCAN_CHUNK + t * 8;
    int v[8];
    int s = 0;
#pragma unroll
    for (int j = 0; j < 8; ++j) {
        int idx = base + j;
        v[j] = (idx < n) ? counts[idx] : 0;
        s += v[j];
    }
    sd[t] = s;
    __syncthreads();
    for (int off = 1; off < 256; off <<= 1) {
        int tmp = 0;
        if (t >= off) tmp = sd[t - off];
        __syncthreads();
        if (t >= off) sd[t] += tmp;
        __syncthreads();
    }
    int run = bsum[blockIdx.x] + sd[t] - s;
#pragma unroll
    for (int j = 0; j < 8; ++j) {
        int idx = base + j;
        if (idx < n) {
            row_ptr[idx] = run;
            cursor[idx] = run;
            run += v[j];
        }
    }
    if (blockIdx.x == 0 && t == 0) row_ptr[n] = total;
}

// scatter edges into CSR slots as packed 16B records {src, w2, (w0|w1)}.
// pos[i] = slot of edge i (coalesced write); attn_norm gathers slot-ordered pbuf.
__global__ void fill_csr(const int* __restrict__ dst, const int* __restrict__ src,
                         const float* __restrict__ vw, int* cursor,
                         int4* __restrict__ recs, int* __restrict__ pos, int e) {
    int i = blockIdx.x * blockDim.x + threadIdx.x;
    if (i < e) {
        int p = atomicAdd(&cursor[dst[i]], 1);
        float w0 = vw[3 * i], w1 = vw[3 * i + 1], w2 = vw[3 * i + 2];
        unsigned u0 = (unsigned)__builtin_bit_cast(unsigned short, (_Float16)w0);
        unsigned u1 = (unsigned)__builtin_bit_cast(unsigned short, (_Float16)w1);
        unsigned u2 = (unsigned)__builtin_bit_cast(unsigned short, (_Float16)w2);
        int4 r;
        r.x = src[i];
        r.y = (int)u2;
        r.z = (int)(u0 | (u1 << 16));
        r.w = 0;
        recs[p] = r;
        pos[i] = p;
    }
}

// transpose+convert W [k][n] fp32 -> wt [n][k] fp16; blockIdx.x selects matrix
__global__ __launch_bounds__(256) void prep_w(const float* __restrict__ Wq,
                                              const float* __restrict__ Wk,
                                              const float* __restrict__ Wv,
                                              _Float16* __restrict__ wt) {
    const float* W = (blockIdx.x == 0) ? Wq : (blockIdx.x == 1) ? Wk : Wv;
    _Float16* out = wt + (size_t)blockIdx.x * 16384;
    int t = threadIdx.x;
    for (int r = 0; r < 64; ++r) {
        int idx = r * 256 + t;          // idx = k*128 + n
        int k = idx >> 7, nn = idx & 127;
        out[nn * 128 + k] = (_Float16)W[idx];
    }
}

// ---------------- fused QKV projection: fp32 x staged once, 3 GEMMs ----------------
// Outputs: qh [node][128] and kvb [node][h][sub][ k8 | v8 ]: a lane's k-half8
// and v-half8 are ADJACENT 16B chunks (same 32B region -> v-load is an L1 hit).

#define LDP 136  // 128 + 8 halfs pad

__global__ __launch_bounds__(256) void qkv_mfma(
    const float* __restrict__ x, const _Float16* __restrict__ wt,
    const float* __restrict__ bq, const float* __restrict__ bk,
    const float* __restrict__ bv,
    _Float16* __restrict__ qh, _Float16* __restrict__ kvb, int n) {
    __shared__ __align__(16) _Float16 xs[128 * LDP];
    __shared__ __align__(16) _Float16 ws[128 * LDP];

    int t = threadIdx.x;
    int tile0 = blockIdx.x * 128;

    // stage x tile fp32 -> fp16 (128 rows x 16 half8 chunks)
#pragma unroll
    for (int r = 0; r < 8; ++r) {
        int id = r * 256 + t;
        int row = id >> 4, c8 = id & 15;
        int grow = tile0 + row;
        half8 val = (half8)(_Float16)0;
        if (grow < n) {
            const float4* s = (const float4*)(x + (size_t)grow * 128 + c8 * 8);
            float4 a = s[0], b = s[1];
            val[0] = (_Float16)a.x; val[1] = (_Float16)a.y;
            val[2] = (_Float16)a.z; val[3] = (_Float16)a.w;
            val[4] = (_Float16)b.x; val[5] = (_Float16)b.y;
            val[6] = (_Float16)b.z; val[7] = (_Float16)b.w;
        }
        *((half8*)(xs + row * LDP) + c8) = val;
    }

    int wave = t >> 6, lane = t & 63;
    int wm = (wave & 1) * 64, wn = (wave >> 1) * 64;
    int lrow = lane & 15, quad = lane >> 4;

    for (int sel = 0; sel < 3; ++sel) {
        const _Float16* wsel = wt + (size_t)sel * 16384;
        const float* bias = (sel == 0) ? bq : (sel == 1) ? bk : bv;

        // stage W^T tile
#pragma unroll
        for (int r = 0; r < 8; ++r) {
            int id = r * 256 + t;
            int row = id >> 4, c8 = id & 15;
            half8 wv = *((const half8*)(wsel + row * 128) + c8);
            *((half8*)(ws + row * LDP) + c8) = wv;
        }
        __syncthreads();

        floatx4 acc[4][4];
#pragma unroll
        for (int i = 0; i < 4; ++i)
#pragma unroll
            for (int j = 0; j < 4; ++j) acc[i][j] = (floatx4)0.f;

#pragma unroll
        for (int kk = 0; kk < 4; ++kk) {
            int kbase = kk * 32 + quad * 8;
            half8 a[4], b[4];
#pragma unroll
            for (int i = 0; i < 4; ++i)
                a[i] = *(const half8*)(xs + (wm + i * 16 + lrow) * LDP + kbase);
#pragma unroll
            for (int j = 0; j < 4; ++j)
                b[j] = *(const half8*)(ws + (wn + j * 16 + lrow) * LDP + kbase);
#pragma unroll
            for (int i = 0; i < 4; ++i)
#pragma unroll
                for (int j = 0; j < 4; ++j)
                    acc[i][j] = __builtin_amdgcn_mfma_f32_16x16x32_f16(a[i], b[j], acc[i][j], 0, 0, 0);
        }

        // epilogue: C row = wm+i*16+quad*4+reg, col = wn+j*16+lrow
#pragma unroll
        for (int i = 0; i < 4; ++i) {
#pragma unroll
            for (int j = 0; j < 4; ++j) {
                int col = wn + j * 16 + lrow;
                float bv_ = bias[col];
                int h = col >> 4, dh = col & 15;
                int sub = dh >> 3, w = dh & 7;
#pragma unroll
                for (int r = 0; r < 4; ++r) {
                    int row = wm + i * 16 + quad * 4 + r;
                    int grow = tile0 + row;
                    if (grow < n) {
                        _Float16 val = (_Float16)(acc[i][j][r] + bv_);
                        if (sel == 0)
                            qh[(size_t)grow * 128 + col] = val;
                        else
                            kvb[(size_t)grow * 256 + h * 32 + sub * 16 +
                                (sel == 2 ? 8 : 0) + w] = val;
                    }
                }
            }
        }
        __syncthreads();  // all waves done with ws before next sel restages
    }
}

// ---------------- Node-centric attention: 16 thr/node, depth-2 pipeline ----------------
// r5-proven structure: 2 lanes/head, depth-2 named KV slots, slot-ordered pbuf,
// packed-record mix. 128-thread blocks (8 nodes, 2 waves/wg) clear the per-CU
// workgroup-slot cap (r6: +18% occupancy) and __launch_bounds__(128,6) keeps
// the VGPR cap at 85 so the pipeline is NOT spilled (r6's (128,8)->32 VGPR
// forced the pipeline to scratch: +330MB sym. FETCH/WRITE, 2x slower).
// K/V interleaved per (node,h,sub): k8|v8 adjacent 16B -> v-load L1-hits.

#define STAGE_META(S, idx)                                                    \
    {                                                                         \
        s##S = 0; m##S = 0.f;                                                 \
        if ((idx) < end) {                                                    \
            int4 r_ = recs[(idx)];                                            \
            s##S = r_.x;                                                      \
            half2v w01_ = __builtin_bit_cast(half2v, r_.z);                   \
            _Float16 w2_ =                                                    \
                __builtin_bit_cast(_Float16, (unsigned short)(unsigned)r_.y); \
            m##S = fmaf(p0, (float)w01_[0],                                   \
                        fmaf(p1, (float)w01_[1], p2 * (float)w2_));           \
        }                                                                     \
    }

#define ISSUE_KV(S, idx)                                                      \
    {                                                                         \
        k##S = (half8)(_Float16)0; v##S = (half8)(_Float16)0;                 \
        if ((idx) < end) {                                                    \
            const _Float16* kp_ = kvbase + (size_t)s##S * 256;                \
            k##S = *(const half8*)(kp_);                                      \
            v##S = *(const half8*)(kp_ + 8);                                  \
        }                                                                     \
    }

#ifdef USE_FDOT2
#define DOT8(dres, kS)                                                        \
    {                                                                         \
        _Pragma("unroll")                                                     \
        for (int jj_ = 0; jj_ < 4; ++jj_) {                                   \
            half2v x_, y_;                                                    \
            x_[0] = qv[2 * jj_]; x_[1] = qv[2 * jj_ + 1];                     \
            y_[0] = kS[2 * jj_]; y_[1] = kS[2 * jj_ + 1];                     \
            dres = __builtin_amdgcn_fdot2(x_, y_, dres, false);               \
        }                                                                     \
    }
#else
#define DOT8(dres, kS)                                                        \
    {                                                                         \
        _Pragma("unroll")                                                     \
        for (int jj_ = 0; jj_ < 8; ++jj_)                                     \
            dres = fmaf((float)qv[jj_], (float)kS[jj_], dres);                \
    }
#endif

#define COMPUTE(S, mx, slot, validc)                                          \
    {                                                                         \
        float d_ = 0.f;                                                       \
        DOT8(d_, k##S);                                                       \
        d_ += __shfl_xor(d_, 1, 64);                                          \
        float p_ = ((mx) > 0.f) ? (mx)*__expf(d_ * 0.25f) : 0.f;              \
        if (sub == 0 && (validc)) pbuf[(size_t)(slot)*8 + h] = (_Float16)p_;  \
        l += p_;                                                              \
        a0 = fmaf(p_, (float)v##S[0], a0);                                    \
        a1 = fmaf(p_, (float)v##S[1], a1);                                    \
        a2 = fmaf(p_, (float)v##S[2], a2);                                    \
        a3 = fmaf(p_, (float)v##S[3], a3);                                    \
        a4 = fmaf(p_, (float)v##S[4], a4);                                    \
        a5 = fmaf(p_, (float)v##S[5], a5);                                    \
        a6 = fmaf(p_, (float)v##S[6], a6);                                    \
        a7 = fmaf(p_, (float)v##S[7], a7);                                    \
    }

#define BODY(S0, S1, S2, S3, jj)                                              \
    {                                                                         \
        ISSUE_KV(S2, (jj) + 2);                                               \
        ISSUE_KV(S3, (jj) + 3);                                               \
        float mx0_ = m##S0, mx1_ = m##S1;                                     \
        STAGE_META(S0, (jj) + 4);                                             \
        STAGE_META(S1, (jj) + 5);                                             \
        COMPUTE(S0, mx0_, (jj), true);                                        \
        COMPUTE(S1, mx1_, (jj) + 1, (jj) + 1 < end);                          \
    }

__global__ __launch_bounds__(128, 6) void edge_attn(
    const _Float16* __restrict__ qh, const _Float16* __restrict__ kvb,
    const float* __restrict__ pi,
    const int* __restrict__ row_ptr, const int4* __restrict__ recs,
    float* __restrict__ node_out, float* __restrict__ invb,
    _Float16* __restrict__ pbuf, int n) {
    int t = threadIdx.x;
    int node = blockIdx.x * 8 + (t >> 4);
    if (node >= n) return;
    int q16 = t & 15;
    int h = q16 >> 1, sub = q16 & 1;
    int off = h * 16 + sub * 8;  // element offset within 128-wide q row

    const half8 qv = *(const half8*)(qh + (size_t)node * 128 + off);
    const _Float16* kvbase = kvb + h * 32 + sub * 16;  // + s*256 -> k8|v8

    float p0 = pi[node * 24 + h * 3 + 0];
    float p1 = pi[node * 24 + h * 3 + 1];
    float p2 = pi[node * 24 + h * 3 + 2];
    int beg = row_ptr[node], end = row_ptr[node + 1];

    float l = 0.f;
    float a0 = 0.f, a1 = 0.f, a2 = 0.f, a3 = 0.f;
    float a4 = 0.f, a5 = 0.f, a6 = 0.f, a7 = 0.f;

    int sA, sB, sC, sD;
    float mA, mB, mC, mD;
    half8 kA, vA, kB, vB, kC, vC, kD, vD;

    STAGE_META(A, beg);
    STAGE_META(B, beg + 1);
    STAGE_META(C, beg + 2);
    STAGE_META(D, beg + 3);
    ISSUE_KV(A, beg);
    ISSUE_KV(B, beg + 1);

    for (int j = beg; j < end;) {
        BODY(A, B, C, D, j);
        j += 2;
        if (j >= end) break;
        BODY(C, D, A, B, j);
        j += 2;
    }

    float inv = 1.f / fmaxf(l, 1e-8f);
    if (sub == 0) invb[(size_t)node * 8 + h] = inv;

    float4* op = (float4*)(node_out + (size_t)node * 128 + off);
    op[0] = make_float4(a0 * inv, a1 * inv, a2 * inv, a3 * inv);
    op[1] = make_float4(a4 * inv, a5 * inv, a6 * inv, a7 * inv);
}

// ---------------- edge-parallel attention normalize ----------------
// pbuf slot-ordered; pos[i] maps edge -> slot (coalesced 4B read). pbuf gather
// is 16B from an L2/L3-resident 25.6MB buffer. Output write coalesced.

__global__ __launch_bounds__(256) void attn_norm(
    const _Float16* __restrict__ pbuf, const int* __restrict__ dst,
    const int* __restrict__ pos, const float* __restrict__ invb,
    float* __restrict__ attn_out, int e) {
    int i = blockIdx.x * blockDim.x + threadIdx.x;
    if (i < e) {
        int d = dst[i];
        int p = pos[i];
        half8 pv = *((const half8*)pbuf + p);
        const float4* iv = (const float4*)(invb + (size_t)d * 8);
        float4 i0 = iv[0], i1 = iv[1];
        float4* op = (float4*)(attn_out + (size_t)i * 8);
        op[0] = make_float4((float)pv[0] * i0.x, (float)pv[1] * i0.y,
                            (float)pv[2] * i0.z, (float)pv[3] * i0.w);
        op[1] = make_float4((float)pv[4] * i1.x, (float)pv[5] * i1.y,
                            (float)pv[6] * i1.z, (float)pv[7] * i1.w);
    }
}

// ---------------- launch ----------------

extern "C" void kernel_launch(void* const* d_in, const int* in_sizes, int n_in,
                              void* d_out, int out_size, void* d_ws, size_t ws_size,
                              hipStream_t stream) {
    const float* x  = (const float*)d_in[0];
    const float* pi = (const float*)d_in[1];
    const float* vw = (const float*)d_in[2];
    const float* Wq = (const float*)d_in[3];
    const float* bq = (const float*)d_in[4];
    const float* Wk = (const float*)d_in[5];
    const float* bk = (const float*)d_in[6];
    const float* Wv = (const float*)d_in[7];
    const float* bv = (const float*)d_in[8];
    const int* src  = (const int*)d_in[9];
    const int* dst  = (const int*)d_in[10];

    int n = in_sizes[0] / 128;  // 100000
    int e = in_sizes[9];        // 1600000

    _Float16* qh  = (_Float16*)d_ws;
    _Float16* kvb = qh + (size_t)n * 128;
    _Float16* wt  = kvb + (size_t)n * 256;
    _Float16* pbuf = wt + 3 * 16384;
    float* invb  = (float*)(pbuf + (size_t)e * 8);
    int* counts  = (int*)(invb + (size_t)n * 8);
    int* cursor  = counts + n;
    int* row_ptr = cursor + n;
    int* bsum    = row_ptr + n + 1;
    int* pos     = bsum + 64;

    float* node_out = (float*)d_out;
    float* attn_out = node_out + (size_t)n * 128;
    // recs scratch (16B/edge = 25.6MB) lives in the 51.2MB attn output region:
    // written by fill_csr, consumed by edge_attn, overwritten by attn_norm.
    int4* recs = (int4*)attn_out;

    hipMemsetAsync(counts, 0, (size_t)n * sizeof(int), stream);

    int eb = (e + 255) / 256;
    hist_kernel<<<eb, 256, 0, stream>>>(dst, counts, e);

    int nb = (n + SCAN_CHUNK - 1) / SCAN_CHUNK;  // 49
    scan_block_sums<<<nb, 256, 0, stream>>>(counts, bsum, n);
    scan_wave<<<1, 64, 0, stream>>>(bsum, nb);
    scan_write<<<nb, 256, 0, stream>>>(counts, bsum, row_ptr, cursor, n, e);
    fill_csr<<<eb, 256, 0, stream>>>(dst, src, vw, cursor, recs, pos, e);

    prep_w<<<3, 256, 0, stream>>>(Wq, Wk, Wv, wt);

    int gtiles = (n + 127) / 128;
    qkv_mfma<<<gtiles, 256, 0, stream>>>(x, wt, bq, bk, bv, qh, kvb, n);

    int gb = (n + 7) / 8;
    edge_attn<<<gb, 128, 0, stream>>>(qh, kvb, pi, row_ptr, recs,
                                      node_out, invb, pbuf, n);
    attn_norm<<<eb, 256, 0, stream>>>(pbuf, dst, pos, invb, attn_out, e);
}

// Round 8
// 611.907 us; speedup vs baseline: 1.3054x; 1.0462x over previous
//
#include <hip/hip_runtime.h>
#include <hip/hip_bf16.h>
#include <math.h>

#define SCAN_CHUNK 2048

typedef _Float16 half2v __attribute__((ext_vector_type(2)));
typedef _Float16 half4v __attribute__((ext_vector_type(4)));
typedef _Float16 half8 __attribute__((ext_vector_type(8)));
typedef float floatx4 __attribute__((ext_vector_type(4)));

#if defined(__has_builtin)
#if __has_builtin(__builtin_amdgcn_fdot2)
#define USE_FDOT2 1
#endif
#endif

// ---------------- CSR build ----------------

__global__ void hist_kernel(const int* __restrict__ dst, int* __restrict__ counts, int e) {
    int i = blockIdx.x * blockDim.x + threadIdx.x;
    if (i < e) atomicAdd(&counts[dst[i]], 1);
}

__global__ __launch_bounds__(256) void scan_block_sums(const int* __restrict__ counts,
                                                       int* __restrict__ bsum, int n) {
    __shared__ int sd[256];
    int t = threadIdx.x;
    int base = blockIdx.x * SCAN_CHUNK + t * 8;
    int s = 0;
#pragma unroll
    for (int j = 0; j < 8; ++j) {
        int idx = base + j;
        if (idx < n) s += counts[idx];
    }
    sd[t] = s;
    __syncthreads();
    for (int off = 128; off > 0; off >>= 1) {
        if (t < off) sd[t] += sd[t + off];
        __syncthreads();
    }
    if (t == 0) bsum[blockIdx.x] = sd[0];
}

// single-wave exclusive scan over nb <= 64 block sums
__global__ void scan_wave(int* bsum, int nb) {
    int lane = threadIdx.x;
    int orig = (lane < nb) ? bsum[lane] : 0;
    int v = orig;
    for (int off = 1; off < 64; off <<= 1) {
        int t = __shfl_up(v, off, 64);
        if (lane >= off) v += t;
    }
    if (lane < nb) bsum[lane] = v - orig;  // exclusive
}

__global__ __launch_bounds__(256) void scan_write(const int* __restrict__ counts,
                                                  const int* __restrict__ bsum,
                                                  int* __restrict__ row_ptr,
                                                  int* __restrict__ cursor,
                                                  int n, int total) {
    __shared__ int sd[256];
    int t = threadIdx.x;
    int base = blockIdx.x * SCAN_CHUNK + t * 8;
    int v[8];
    int s = 0;
#pragma unroll
    for (int j = 0; j < 8; ++j) {
        int idx = base + j;
        v[j] = (idx < n) ? counts[idx] : 0;
        s += v[j];
    }
    sd[t] = s;
    __syncthreads();
    for (int off = 1; off < 256; off <<= 1) {
        int tmp = 0;
        if (t >= off) tmp = sd[t - off];
        __syncthreads();
        if (t >= off) sd[t] += tmp;
        __syncthreads();
    }
    int run = bsum[blockIdx.x] + sd[t] - s;
#pragma unroll
    for (int j = 0; j < 8; ++j) {
        int idx = base + j;
        if (idx < n) {
            row_ptr[idx] = run;
            cursor[idx] = run;
            run += v[j];
        }
    }
    if (blockIdx.x == 0 && t == 0) row_ptr[n] = total;
}

// scatter edges into CSR slots as packed 16B records {src, w2, (w0|w1)}.
// pos[i] = slot of edge i (coalesced write); attn_norm gathers slot-ordered pbuf.
__global__ void fill_csr(const int* __restrict__ dst, const int* __restrict__ src,
                         const float* __restrict__ vw, int* cursor,
                         int4* __restrict__ recs, int* __restrict__ pos, int e) {
    int i = blockIdx.x * blockDim.x + threadIdx.x;
    if (i < e) {
        int p = atomicAdd(&cursor[dst[i]], 1);
        float w0 = vw[3 * i], w1 = vw[3 * i + 1], w2 = vw[3 * i + 2];
        unsigned u0 = (unsigned)__builtin_bit_cast(unsigned short, (_Float16)w0);
        unsigned u1 = (unsigned)__builtin_bit_cast(unsigned short, (_Float16)w1);
        unsigned u2 = (unsigned)__builtin_bit_cast(unsigned short, (_Float16)w2);
        int4 r;
        r.x = src[i];
        r.y = (int)u2;
        r.z = (int)(u0 | (u1 << 16));
        r.w = 0;
        recs[p] = r;
        pos[i] = p;
    }
}

// ---------------- fp16 prep ----------------

__global__ __launch_bounds__(256) void convert_x(const float* __restrict__ x,
                                                 _Float16* __restrict__ xh, int total8) {
    int i = blockIdx.x * blockDim.x + threadIdx.x;
    if (i < total8) {
        const float4* s = (const float4*)x + i * 2;
        float4 a = s[0], b = s[1];
        half8 h;
        h[0] = (_Float16)a.x; h[1] = (_Float16)a.y; h[2] = (_Float16)a.z; h[3] = (_Float16)a.w;
        h[4] = (_Float16)b.x; h[5] = (_Float16)b.y; h[6] = (_Float16)b.z; h[7] = (_Float16)b.w;
        *((half8*)xh + i) = h;
    }
}

// transpose+convert W [k][n] fp32 -> wt [n][k] fp16; blockIdx.x selects matrix
__global__ __launch_bounds__(256) void prep_w(const float* __restrict__ Wq,
                                              const float* __restrict__ Wk,
                                              const float* __restrict__ Wv,
                                              _Float16* __restrict__ wt) {
    const float* W = (blockIdx.x == 0) ? Wq : (blockIdx.x == 1) ? Wk : Wv;
    _Float16* out = wt + (size_t)blockIdx.x * 16384;
    int t = threadIdx.x;
    for (int r = 0; r < 64; ++r) {
        int idx = r * 256 + t;          // idx = k*128 + n
        int k = idx >> 7, nn = idx & 127;
        out[nn * 128 + k] = (_Float16)W[idx];
    }
}

// ---------------- QKV projection: fp16 MFMA, split grid (r5-proven) ----------------
// sel=0 -> qh [node][128]; sel=1/2 -> kvb [node][h][sub4][ k4 | v4 ]: a lane's
// k-half4 and v-half4 are ADJACENT 8B chunks (same 16B region -> v-load L1-hits).

#define LDP 136  // 128 + 8 halfs pad

__global__ __launch_bounds__(256) void qkv_mfma(
    const _Float16* __restrict__ xh, const _Float16* __restrict__ wt,
    const float* __restrict__ bq, const float* __restrict__ bk,
    const float* __restrict__ bv,
    _Float16* __restrict__ qh, _Float16* __restrict__ kvb, int n) {
    __shared__ __align__(16) _Float16 xs[128 * LDP];
    __shared__ __align__(16) _Float16 ws[128 * LDP];

    int t = threadIdx.x;
    int tile0 = blockIdx.x * 128;
    int sel = blockIdx.y;
    const _Float16* wsel = wt + (size_t)sel * 16384;
    const float* bias = (sel == 0) ? bq : (sel == 1) ? bk : bv;

#pragma unroll
    for (int r = 0; r < 8; ++r) {
        int id = r * 256 + t;
        int row = id >> 4, c8 = id & 15;
        int grow = tile0 + row;
        half8 val = (half8)(_Float16)0;
        if (grow < n) val = *((const half8*)(xh + (size_t)grow * 128) + c8);
        *((half8*)(xs + row * LDP) + c8) = val;
        half8 wv = *((const half8*)(wsel + row * 128) + c8);
        *((half8*)(ws + row * LDP) + c8) = wv;
    }
    __syncthreads();

    int wave = t >> 6, lane = t & 63;
    int wm = (wave & 1) * 64, wn = (wave >> 1) * 64;
    int lrow = lane & 15, quad = lane >> 4;

    floatx4 acc[4][4];
#pragma unroll
    for (int i = 0; i < 4; ++i)
#pragma unroll
        for (int j = 0; j < 4; ++j) acc[i][j] = (floatx4)0.f;

#pragma unroll
    for (int kk = 0; kk < 4; ++kk) {
        int kbase = kk * 32 + quad * 8;
        half8 a[4], b[4];
#pragma unroll
        for (int i = 0; i < 4; ++i)
            a[i] = *(const half8*)(xs + (wm + i * 16 + lrow) * LDP + kbase);
#pragma unroll
        for (int j = 0; j < 4; ++j)
            b[j] = *(const half8*)(ws + (wn + j * 16 + lrow) * LDP + kbase);
#pragma unroll
        for (int i = 0; i < 4; ++i)
#pragma unroll
            for (int j = 0; j < 4; ++j)
                acc[i][j] = __builtin_amdgcn_mfma_f32_16x16x32_f16(a[i], b[j], acc[i][j], 0, 0, 0);
    }

    // epilogue: C row = wm+i*16+quad*4+reg, col = wn+j*16+lrow
#pragma unroll
    for (int i = 0; i < 4; ++i) {
#pragma unroll
        for (int j = 0; j < 4; ++j) {
            int col = wn + j * 16 + lrow;
            float bv_ = bias[col];
            int h = col >> 4, dh = col & 15;
            int sub = dh >> 2, w = dh & 3;
#pragma unroll
            for (int r = 0; r < 4; ++r) {
                int row = wm + i * 16 + quad * 4 + r;
                int grow = tile0 + row;
                if (grow < n) {
                    _Float16 val = (_Float16)(acc[i][j][r] + bv_);
                    if (sel == 0)
                        qh[(size_t)grow * 128 + col] = val;
                    else
                        kvb[(size_t)grow * 256 + h * 32 + sub * 8 +
                            (sel == 2 ? 4 : 0) + w] = val;
                }
            }
        }
    }
}

// ---------------- Node-centric attention: 32 thr/node, depth-3 pipeline ----------------
// 4 lanes/head, 4 elems each: k/v 2 VGPR per slot-half -> 6 named KV slots fit
// in ~60 VGPR (depth-3 at 16thr/node would spill past the 85-VGPR cap, r6's
// lesson). Depth-3: while computing edges (j,j+1), KV for (j+2..j+5) in flight
// and meta for (j+6,j+7) staging -- ~2 bodies (~1200cy) of latency cover vs
// ~700-900cy L3/HBM gather latency. 2 nodes/wave (less lockstep divergence).
// mix from packed slot record (broadcast int4). pbuf slot-indexed.

#define STAGE_META(S, idx)                                                    \
    {                                                                         \
        s##S = 0; m##S = 0.f;                                                 \
        if ((idx) < end) {                                                    \
            int4 r_ = recs[(idx)];                                            \
            s##S = r_.x;                                                      \
            half2v w01_ = __builtin_bit_cast(half2v, r_.z);                   \
            _Float16 w2_ =                                                    \
                __builtin_bit_cast(_Float16, (unsigned short)(unsigned)r_.y); \
            m##S = fmaf(p0, (float)w01_[0],                                   \
                        fmaf(p1, (float)w01_[1], p2 * (float)w2_));           \
        }                                                                     \
    }

#define ISSUE_KV(S, idx)                                                      \
    {                                                                         \
        k##S = (half4v)(_Float16)0; v##S = (half4v)(_Float16)0;               \
        if ((idx) < end) {                                                    \
            const _Float16* kp_ = kvbase + (size_t)s##S * 256;                \
            k##S = *(const half4v*)(kp_);                                     \
            v##S = *(const half4v*)(kp_ + 4);                                 \
        }                                                                     \
    }

#ifdef USE_FDOT2
#define DOT4(dres, kS)                                                        \
    {                                                                         \
        half2v x_, y_;                                                        \
        x_[0] = qv[0]; x_[1] = qv[1]; y_[0] = kS[0]; y_[1] = kS[1];           \
        dres = __builtin_amdgcn_fdot2(x_, y_, dres, false);                   \
        x_[0] = qv[2]; x_[1] = qv[3]; y_[0] = kS[2]; y_[1] = kS[3];           \
        dres = __builtin_amdgcn_fdot2(x_, y_, dres, false);                   \
    }
#else
#define DOT4(dres, kS)                                                        \
    {                                                                         \
        _Pragma("unroll")                                                     \
        for (int jj_ = 0; jj_ < 4; ++jj_)                                     \
            dres = fmaf((float)qv[jj_], (float)kS[jj_], dres);                \
    }
#endif

#define COMPUTE(S, mx, slot, validc)                                          \
    {                                                                         \
        float d_ = 0.f;                                                       \
        DOT4(d_, k##S);                                                       \
        d_ += __shfl_xor(d_, 1, 64);                                          \
        d_ += __shfl_xor(d_, 2, 64);                                          \
        float p_ = ((mx) > 0.f) ? (mx)*__expf(d_ * 0.25f) : 0.f;              \
        if (sub == 0 && (validc)) pbuf[(size_t)(slot)*8 + h] = (_Float16)p_;  \
        l += p_;                                                              \
        a0 = fmaf(p_, (float)v##S[0], a0);                                    \
        a1 = fmaf(p_, (float)v##S[1], a1);                                    \
        a2 = fmaf(p_, (float)v##S[2], a2);                                    \
        a3 = fmaf(p_, (float)v##S[3], a3);                                    \
    }

// computes (jj, jj+1) from S0,S1; issues KV for (jj+4,jj+5) into SI0,SI1
// (meta staged two bodies earlier); stages meta (jj+6,jj+7) into S0,S1.
#define BODY(S0, S1, SI0, SI1, jj)                                            \
    {                                                                         \
        ISSUE_KV(SI0, (jj) + 4);                                              \
        ISSUE_KV(SI1, (jj) + 5);                                              \
        float mx0_ = m##S0, mx1_ = m##S1;                                     \
        STAGE_META(S0, (jj) + 6);                                             \
        STAGE_META(S1, (jj) + 7);                                             \
        COMPUTE(S0, mx0_, (jj), true);                                        \
        COMPUTE(S1, mx1_, (jj) + 1, (jj) + 1 < end);                          \
    }

__global__ __launch_bounds__(128, 6) void edge_attn(
    const _Float16* __restrict__ qh, const _Float16* __restrict__ kvb,
    const float* __restrict__ pi,
    const int* __restrict__ row_ptr, const int4* __restrict__ recs,
    float* __restrict__ node_out, float* __restrict__ invb,
    _Float16* __restrict__ pbuf, int n) {
    int t = threadIdx.x;
    int node = blockIdx.x * 4 + (t >> 5);
    if (node >= n) return;
    int q32 = t & 31;
    int h = q32 >> 2, sub = q32 & 3;
    int off = h * 16 + sub * 4;  // element offset within 128-wide q row

    const half4v qv = *(const half4v*)(qh + (size_t)node * 128 + off);
    const _Float16* kvbase = kvb + h * 32 + sub * 8;  // + s*256 -> k4|v4

    float p0 = pi[node * 24 + h * 3 + 0];
    float p1 = pi[node * 24 + h * 3 + 1];
    float p2 = pi[node * 24 + h * 3 + 2];
    int beg = row_ptr[node], end = row_ptr[node + 1];

    float l = 0.f;
    float a0 = 0.f, a1 = 0.f, a2 = 0.f, a3 = 0.f;

    int sA, sB, sC, sD, sE, sF;
    float mA, mB, mC, mD, mE, mF;
    half4v kA, vA, kB, vB, kC, vC, kD, vD, kE, vE, kF, vF;

    STAGE_META(A, beg);
    STAGE_META(B, beg + 1);
    STAGE_META(C, beg + 2);
    STAGE_META(D, beg + 3);
    STAGE_META(E, beg + 4);
    STAGE_META(F, beg + 5);
    ISSUE_KV(A, beg);
    ISSUE_KV(B, beg + 1);
    ISSUE_KV(C, beg + 2);
    ISSUE_KV(D, beg + 3);

    for (int j = beg; j < end;) {
        BODY(A, B, E, F, j);
        j += 2;
        if (j >= end) break;
        BODY(C, D, A, B, j);
        j += 2;
        if (j >= end) break;
        BODY(E, F, C, D, j);
        j += 2;
    }

    float inv = 1.f / fmaxf(l, 1e-8f);
    if (sub == 0) invb[(size_t)node * 8 + h] = inv;

    float4* op = (float4*)(node_out + (size_t)node * 128 + off);
    op[0] = make_float4(a0 * inv, a1 * inv, a2 * inv, a3 * inv);
}

// ---------------- edge-parallel attention normalize ----------------
// pbuf slot-ordered; pos[i] maps edge -> slot (coalesced 4B read). pbuf gather
// is 16B from an L2/L3-resident 25.6MB buffer. Output write coalesced.

__global__ __launch_bounds__(256) void attn_norm(
    const _Float16* __restrict__ pbuf, const int* __restrict__ dst,
    const int* __restrict__ pos, const float* __restrict__ invb,
    float* __restrict__ attn_out, int e) {
    int i = blockIdx.x * blockDim.x + threadIdx.x;
    if (i < e) {
        int d = dst[i];
        int p = pos[i];
        half8 pv = *((const half8*)pbuf + p);
        const float4* iv = (const float4*)(invb + (size_t)d * 8);
        float4 i0 = iv[0], i1 = iv[1];
        float4* op = (float4*)(attn_out + (size_t)i * 8);
        op[0] = make_float4((float)pv[0] * i0.x, (float)pv[1] * i0.y,
                            (float)pv[2] * i0.z, (float)pv[3] * i0.w);
        op[1] = make_float4((float)pv[4] * i1.x, (float)pv[5] * i1.y,
                            (float)pv[6] * i1.z, (float)pv[7] * i1.w);
    }
}

// ---------------- launch ----------------

extern "C" void kernel_launch(void* const* d_in, const int* in_sizes, int n_in,
                              void* d_out, int out_size, void* d_ws, size_t ws_size,
                              hipStream_t stream) {
    const float* x  = (const float*)d_in[0];
    const float* pi = (const float*)d_in[1];
    const float* vw = (const float*)d_in[2];
    const float* Wq = (const float*)d_in[3];
    const float* bq = (const float*)d_in[4];
    const float* Wk = (const float*)d_in[5];
    const float* bk = (const float*)d_in[6];
    const float* Wv = (const float*)d_in[7];
    const float* bv = (const float*)d_in[8];
    const int* src  = (const int*)d_in[9];
    const int* dst  = (const int*)d_in[10];

    int n = in_sizes[0] / 128;  // 100000
    int e = in_sizes[9];        // 1600000

    _Float16* xh  = (_Float16*)d_ws;
    _Float16* qh  = xh + (size_t)n * 128;
    _Float16* kvb = qh + (size_t)n * 128;
    _Float16* wt  = kvb + (size_t)n * 256;
    _Float16* pbuf = wt + 3 * 16384;
    float* invb  = (float*)(pbuf + (size_t)e * 8);
    int* counts  = (int*)(invb + (size_t)n * 8);
    int* cursor  = counts + n;
    int* row_ptr = cursor + n;
    int* bsum    = row_ptr + n + 1;
    int* pos     = bsum + 64;

    float* node_out = (float*)d_out;
    float* attn_out = node_out + (size_t)n * 128;
    // recs scratch (16B/edge = 25.6MB) lives in the 51.2MB attn output region:
    // written by fill_csr, consumed by edge_attn, overwritten by attn_norm.
    int4* recs = (int4*)attn_out;

    hipMemsetAsync(counts, 0, (size_t)n * sizeof(int), stream);

    int eb = (e + 255) / 256;
    hist_kernel<<<eb, 256, 0, stream>>>(dst, counts, e);

    int nb = (n + SCAN_CHUNK - 1) / SCAN_CHUNK;  // 49
    scan_block_sums<<<nb, 256, 0, stream>>>(counts, bsum, n);
    scan_wave<<<1, 64, 0, stream>>>(bsum, nb);
    scan_write<<<nb, 256, 0, stream>>>(counts, bsum, row_ptr, cursor, n, e);
    fill_csr<<<eb, 256, 0, stream>>>(dst, src, vw, cursor, recs, pos, e);

    int tot8 = (n * 128) / 8;
    convert_x<<<(tot8 + 255) / 256, 256, 0, stream>>>(x, xh, tot8);
    prep_w<<<3, 256, 0, stream>>>(Wq, Wk, Wv, wt);

    int gtiles = (n + 127) / 128;
    qkv_mfma<<<dim3(gtiles, 3), 256, 0, stream>>>(xh, wt, bq, bk, bv, qh, kvb, n);

    int gb = (n + 3) / 4;
    edge_attn<<<gb, 128, 0, stream>>>(qh, kvb, pi, row_ptr, recs,
                                      node_out, invb, pbuf, n);
    attn_norm<<<eb, 256, 0, stream>>>(pbuf, dst, pos, invb, attn_out, e);
}